// Round 16
// baseline (250.651 us; speedup 1.0000x reference)
//
#include <hip/hip_runtime.h>
#include <math.h>

#define BATCH 2
#define INC   64
#define OUTCH 128
#define NP    8
#define DD    12
#define HH    48
#define WW    48
#define HW    (HH*WW)         // 2304
#define DHW   (DD*HW)         // 27648
#define SPTS  (BATCH*DHW)     // 55296
#define KDIM  (INC*NP)        // 512
#define NELEM (BATCH*OUTCH*DHW) // 7077888
#define VSTRIDE 516           // bf16 elems per p-row in LDS for GEMM2 B (usage 512, pad 4)

// workspace layout (floats) — total 3,203,328 floats = 12.81 MB
#define WS_W2B  0                          // ushort[65536]: GEMM2 A bf16 fragments
#define WS_W3   32768                      // float[55296]: conv weights [ic][27][32] (24 used)
#define WS_PART 88064                      // (legacy slot, unused)
#define WS_XT   90112                      // uint[1769472]: x as [b][s][ic/2] bf16x2
#define WS_OFF  1859584                    // float[SPTS*24]: offset-conv output [s][24]
#define WS_PSQ  3186688                    // float[16384]: S[c*64+slot] then Q at +8192
#define WS_PF   3203072                    // float[256]: final sums [c], ssq [128+c]

typedef __attribute__((ext_vector_type(8))) short short8;
typedef __attribute__((ext_vector_type(4))) float floatx4;

__device__ __forceinline__ ushort f2bf(float f) {
    unsigned u = __float_as_uint(f);
    unsigned r = (u + 0x7fffu + ((u >> 16) & 1u)) >> 16;
    return (ushort)r;
}

__device__ __forceinline__ unsigned interp2(unsigned a, unsigned b, unsigned c, unsigned d,
                                            float g0, float g1, float g2, float g3) {
    float vl = g0 * __uint_as_float(a << 16) + g1 * __uint_as_float(b << 16)
             + g2 * __uint_as_float(c << 16) + g3 * __uint_as_float(d << 16);
    float vh = g0 * __uint_as_float(a & 0xffff0000u) + g1 * __uint_as_float(b & 0xffff0000u)
             + g2 * __uint_as_float(c & 0xffff0000u) + g3 * __uint_as_float(d & 0xffff0000u);
    return (unsigned)f2bf(vl) | ((unsigned)f2bf(vh) << 16);
}

// ---- prep 0a: wc [oc][ic][n] -> w2b bf16 fragment layout [(kq*128+oc)*8+j], e=kq*8+j=n*64+ic
__global__ __launch_bounds__(256) void k_prep_w2b(const float* __restrict__ wc,
                                                  ushort* __restrict__ w2b) {
    int t = blockIdx.x * 256 + threadIdx.x;   // 65536
    int j  = t & 7;
    int oc = (t >> 3) & 127;
    int kq = t >> 10;
    int e  = kq * 8 + j;
    int ic = e & 63;
    int n  = e >> 6;
    w2b[t] = f2bf(wc[(oc * INC + ic) * NP + n]);
}

// ---- prep 0b: w_p -> w3c float[(ic*27+tt)*32 + ch]; ALSO zero-inits the BN stat slots
// (runs before k_fused each launch -> replay-idempotent, no extra kernel).
__global__ __launch_bounds__(256) void k_prep_w3(const float* __restrict__ wp,
                                                 float* __restrict__ w3c,
                                                 float* __restrict__ psq) {
    int t = blockIdx.x * 256 + threadIdx.x;   // 64*27*32 = 55296
    if (t < 16384) psq[t] = 0.f;
    int ch = t & 31;
    int iu = t >> 5;                          // ic*27+tt, 0..1727
    w3c[t] = (ch < 24) ? wp[ch * 1728 + iu] : 0.f;
}

// ---- prep 0c v2: LDS tile transpose — coalesced reads (was stride-221KB scatter).
// Block = one batch-local 64-s x 64-ic tile. Load: lane-consecutive-in-s (256B/wave);
// one barrier; write packed bf16 pairs xTu[(q0+sj)*32+icp] (128B/half-wave). Output
// bit-identical to the old kernel: same f2bf on the same floats, same layout.
__global__ __launch_bounds__(256) void k_transpose_x(const float* __restrict__ x,
                                                     unsigned* __restrict__ xTu) {
    __shared__ float sX[64 * 65];             // 16,640 B; pad 65 breaks bank aliasing
    int t  = threadIdx.x;
    int q0 = blockIdx.x * 64;                 // DHW%64==0 -> tile in one batch
    int bb = q0 / DHW;
    int s0 = q0 - bb * DHW;
    const float* xb = x + (size_t)bb * INC * DHW + s0;

    int si  = t & 63;
    int icL = t >> 6;                         // 0..3
    #pragma unroll
    for (int k = 0; k < 16; ++k) {
        int ic = k * 4 + icL;
        sX[ic * 65 + si] = xb[(size_t)ic * DHW + si];
    }
    __syncthreads();

    int icp = t & 31;
    int sjb = t >> 5;                         // 0..7
    #pragma unroll
    for (int pass = 0; pass < 8; ++pass) {
        int sj = pass * 8 + sjb;
        float v0 = sX[(2 * icp)     * 65 + sj];
        float v1 = sX[(2 * icp + 1) * 65 + sj];
        xTu[(size_t)(q0 + sj) * 32 + icp] = (unsigned)f2bf(v0) | ((unsigned)f2bf(v1) << 16);
    }
}

// ---- standalone fp32 offset conv: R7 champion, byte-identical (123us floor, proven).
// CRITICAL NUMERIC INVARIANT (R2 failure): each channel's fmaf chain must be bitwise
// identical to the original — seed bp[ch], then fmaf over (kz, ic=0..63, u=0..8)
// lexicographic, all within ONE thread. Only points and channels split across threads.
// Scoreboard R7..R14: all restructurings land 123-151us; 123 is the floor — frozen.
__global__ __launch_bounds__(256, 4) void k_conv(const float* __restrict__ x,
                                                 const float* __restrict__ w3c,
                                                 const float* __restrict__ bp,
                                                 float* __restrict__ off) {
    int t    = threadIdx.x;
    int lane = t & 63;
    int hgq  = __builtin_amdgcn_readfirstlane(t >> 6);   // 0..3: channel sextet, wave-uniform
    int q0 = blockIdx.x * 128;        // 128 pts/block; HW%128==0 -> one (batch, z-plane)
    int bb = q0 / DHW;
    int s0 = q0 - bb * DHW;
    int dp = s0 / HW;                 // block-uniform z
    int rp = s0 - dp * HW + 2 * lane;
    int hp = rp / WW;
    int c0 = rp - hp * WW;            // even, 0..46; pair never crosses a row (WW%2==0)
    const float* xb = x + (size_t)bb * INC * DHW;
    const float* wbase = w3c + hgq * 6;

    int rAo = (hp > 0      ? hp - 1 : 0     ) * WW;   // kx=0 row
    int rMo = hp * WW;                                // kx=1 row
    int rBo = (hp < HH - 1 ? hp + 1 : HH - 1) * WW;   // kx=2 row
    int oL = (c0 > 0)  ? c0 - 2 : 0;    // float2 holding col c0-1 (L.y)
    int oM = c0;                        // cols c0, c0+1
    int oR = (c0 < 46) ? c0 + 2 : 46;   // float2 holding col c0+2 (R.x)

    float rm0 = (hp > 0)      ? 1.f : 0.f;
    float rm2 = (hp < HH - 1) ? 1.f : 0.f;
    float clm = (c0 > 0)      ? 1.f : 0.f;   // pt0 ky=0 col mask
    float crm = (c0 < 46)     ? 1.f : 0.f;   // pt1 ky=2 col mask
    float m0[9], m1[9];
    #pragma unroll
    for (int kx = 0; kx < 3; ++kx) {
        float rmv = kx == 0 ? rm0 : (kx == 1 ? 1.f : rm2);
        #pragma unroll
        for (int ky = 0; ky < 3; ++ky) {
            int u = kx * 3 + ky;
            m0[u] = rmv * (ky == 0 ? clm : 1.f);
            m1[u] = rmv * (ky == 2 ? crm : 1.f);
        }
    }

    float acc[2][6];
    #pragma unroll
    for (int c = 0; c < 6; ++c) { acc[0][c] = bp[hgq * 6 + c]; acc[1][c] = bp[hgq * 6 + c]; }

    #pragma unroll 1
    for (int kz = 0; kz < 3; ++kz) {
        int z = dp + kz - 1;
        if ((unsigned)z >= DD) continue;     // block-uniform; skips only exact +-0 adds
        const float* xz = xb + z * HW;
        #pragma unroll 2
        for (int ic = 0; ic < 64; ++ic) {
            const float* xp = xz + (size_t)ic * DHW;
            float2 LA = *reinterpret_cast<const float2*>(xp + rAo + oL);
            float2 MA = *reinterpret_cast<const float2*>(xp + rAo + oM);
            float2 RA = *reinterpret_cast<const float2*>(xp + rAo + oR);
            float2 LM = *reinterpret_cast<const float2*>(xp + rMo + oL);
            float2 MM = *reinterpret_cast<const float2*>(xp + rMo + oM);
            float2 RM = *reinterpret_cast<const float2*>(xp + rMo + oR);
            float2 LB = *reinterpret_cast<const float2*>(xp + rBo + oL);
            float2 MB = *reinterpret_cast<const float2*>(xp + rBo + oM);
            float2 RB = *reinterpret_cast<const float2*>(xp + rBo + oR);
            const float* wk = wbase + (ic * 27 + kz * 9) * 32;
            #pragma unroll
            for (int kx = 0; kx < 3; ++kx) {
                float tv[4];
                if (kx == 0)      { tv[0] = LA.y; tv[1] = MA.x; tv[2] = MA.y; tv[3] = RA.x; }
                else if (kx == 1) { tv[0] = LM.y; tv[1] = MM.x; tv[2] = MM.y; tv[3] = RM.x; }
                else              { tv[0] = LB.y; tv[1] = MB.x; tv[2] = MB.y; tv[3] = RB.x; }
                #pragma unroll
                for (int ky = 0; ky < 3; ++ky) {
                    int u = kx * 3 + ky;
                    const float* w6 = wk + u * 32;
                    float xv0 = tv[ky]     * m0[u];
                    float xv1 = tv[ky + 1] * m1[u];
                    #pragma unroll
                    for (int c = 0; c < 6; ++c) {
                        acc[0][c] = fmaf(xv0, w6[c], acc[0][c]);
                        acc[1][c] = fmaf(xv1, w6[c], acc[1][c]);
                    }
                }
            }
        }
    }

    float2* o0 = reinterpret_cast<float2*>(off + (size_t)(q0 + 2 * lane) * 24 + hgq * 6);
    o0[0] = make_float2(acc[0][0], acc[0][1]);
    o0[1] = make_float2(acc[0][2], acc[0][3]);
    o0[2] = make_float2(acc[0][4], acc[0][5]);
    float2* o1 = reinterpret_cast<float2*>(off + (size_t)(q0 + 2 * lane + 1) * 24 + hgq * 6);
    o1[0] = make_float2(acc[1][0], acc[1][1]);
    o1[1] = make_float2(acc[1][2], acc[1][3]);
    o1[2] = make_float2(acc[1][4], acc[1][5]);
}

// ---- fused v3: geometry + barrier-free direct gather-interp + MFMA GEMM2
//      + fused BN partial stats (saves the 28MB out re-read of k_stats_partial).
// Stats path: deterministic 16-lane shfl_xor tree per channel, then atomicAdd into
// 64-slot accumulators (27 contenders/slot). BN stats are a CONTINUOUS path (no floor
// discontinuity — contrast R2's offset-conv failure), so summation-order changes are
// ulp-level-safe. Slots zeroed in k_prep_w3 each launch.
__global__ __launch_bounds__(256, 4) void k_fused(const unsigned* __restrict__ xTu,
                                                  const float* __restrict__ off,
                                                  const ushort* __restrict__ w2b,
                                                  float* __restrict__ out,
                                                  float* __restrict__ psq) {
    __shared__ __align__(16) ushort sVb[32 * VSTRIDE];   // 33,024 B: V[p][e] bf16
    __shared__ __align__(16) ushort4 sMiP[256];          // 2 KB: 4 corner indices per task
    __shared__ __align__(16) float4  sMgP[256];          // 4 KB: 4 corner weights per task

    int t  = threadIdx.x;
    int q0 = blockIdx.x * 32;        // DHW%32==0 -> block never straddles batch
    int bb = q0 / DHW;

    // ---- geometry (fp32), task t = (i = t>>3, n = t&7): publish corner meta to LDS ----
    {
        int i = t >> 3, n = t & 7;
        int s = q0 + i - bb * DHW;
        int d = s / HW; int r = s - d * HW; int h = r / WW; int w = r - h * WW;

        const float* op = off + (size_t)(q0 + i) * 24;
        float a0 = op[n];
        float a1 = op[8 + n];
        float a2 = op[16 + n];

        float pnz = (n < 6) ? (float)(n / 3) : 2.f;
        float pnx = (n < 6) ? 0.f : 1.f;
        float pny = (n < 6) ? (float)(n % 3) : (float)(n - 6);
        float pz = a0 + (float)d + pnz;
        float px = a1 + (float)h + pnx;
        float py = a2 + (float)w + pny;
        float fz = floorf(pz), fx = floorf(px), fy = floorf(py);
        float z0 = fminf(fmaxf(fz, 0.f), DD - 1.f), z1 = fminf(fmaxf(fz + 1.f, 0.f), DD - 1.f);
        float x0 = fminf(fmaxf(fx, 0.f), HH - 1.f), x1 = fminf(fmaxf(fx + 1.f, 0.f), HH - 1.f);
        float y0 = fminf(fmaxf(fy, 0.f), WW - 1.f), y1 = fminf(fmaxf(fy + 1.f, 0.f), WW - 1.f);
        float pzc = fminf(fmaxf(pz, 0.f), DD - 1.f);
        float pxc = fminf(fmaxf(px, 0.f), HH - 1.f);
        float pyc = fminf(fmaxf(py, 0.f), WW - 1.f);
        float wz0 = 1.f + z0 - pzc, wz1 = 1.f - z1 + pzc;
        float wx0 = 1.f + x0 - pxc, wx1 = 1.f - x1 + pxc;
        float wy0 = 1.f + y0 - pyc, wy1 = 1.f - y1 + pyc;
        float c0 = wz0 * wy0, c1 = wz1 * wy1;
        int iz0 = (int)z0, iz1 = (int)z1, ix0 = (int)x0, ix1 = (int)x1, iy0 = (int)y0, iy1 = (int)y1;
        ushort i0 = (ushort)((iz0 * HH + ix0) * WW + iy0);
        ushort i1 = (ushort)((iz0 * HH + ix1) * WW + iy0);
        ushort i2 = (ushort)((iz1 * HH + ix0) * WW + iy1);
        ushort i3 = (ushort)((iz1 * HH + ix1) * WW + iy1);
        sMiP[t] = make_ushort4(i0, i1, i2, i3);
        sMgP[t] = make_float4(c0 * wx0, c0 * wx1, c1 * wx0, c1 * wx1);
    }
    __syncthreads();   // meta ready

    // ---- phase 2: barrier-free direct gather + interp (8 chunks x 32 tasks) ----
    {
        const unsigned* xTb = xTu + (size_t)bb * DHW * 32;
        unsigned* sVbU = reinterpret_cast<unsigned*>(sVb);
        int tk = t >> 3, ch8 = t & 7;    // task-local (0..31), 8-ch octet (0..7)

        #pragma unroll 4
        for (int cc = 0; cc < 8; ++cc) {
            int gt = cc * 32 + tk;
            ushort4 mi = sMiP[gt];       // broadcast ds_read (8 lanes same addr)
            float4  mg = sMgP[gt];
            uint4 A = *reinterpret_cast<const uint4*>(xTb + (size_t)mi.x * 32 + ch8 * 4);
            uint4 B = *reinterpret_cast<const uint4*>(xTb + (size_t)mi.y * 32 + ch8 * 4);
            uint4 C = *reinterpret_cast<const uint4*>(xTb + (size_t)mi.z * 32 + ch8 * 4);
            uint4 D = *reinterpret_cast<const uint4*>(xTb + (size_t)mi.w * 32 + ch8 * 4);
            unsigned o0 = interp2(A.x, B.x, C.x, D.x, mg.x, mg.y, mg.z, mg.w);
            unsigned o1 = interp2(A.y, B.y, C.y, D.y, mg.x, mg.y, mg.z, mg.w);
            unsigned o2 = interp2(A.z, B.z, C.z, D.z, mg.x, mg.y, mg.z, mg.w);
            unsigned o3 = interp2(A.w, B.w, C.w, D.w, mg.x, mg.y, mg.z, mg.w);
            int ii = gt >> 3, nn = gt & 7;
            int wb = ii * (VSTRIDE / 2) + nn * 32 + ch8 * 4;   // even -> 8B aligned
            *reinterpret_cast<uint2*>(&sVbU[wb])     = make_uint2(o0, o1);
            *reinterpret_cast<uint2*>(&sVbU[wb + 2]) = make_uint2(o2, o3);
        }
    }
    __syncthreads();   // sVb complete

    // ---- phase 3: out[128oc x 32p] via mfma_f32_16x16x32_bf16 + BN partials ----
    {
        int lane = t & 63;
        int wid  = t >> 6;
        int l16  = lane & 15;
        int q    = lane >> 4;
        int ocA0 = (wid * 2) * 16 + l16;
        const ushort* A0 = w2b + ((q * 128) + ocA0) * 8;     // +kt*4096
        const ushort* A1 = A0 + 16 * 8;
        const ushort* B0 = sVb + l16 * VSTRIDE + q * 8;      // +kt*32
        const ushort* B1 = B0 + 16 * VSTRIDE;

        floatx4 c00 = {0.f, 0.f, 0.f, 0.f};
        floatx4 c01 = {0.f, 0.f, 0.f, 0.f};
        floatx4 c10 = {0.f, 0.f, 0.f, 0.f};
        floatx4 c11 = {0.f, 0.f, 0.f, 0.f};

        #pragma unroll 4
        for (int kt = 0; kt < 16; ++kt) {
            short8 af0 = *reinterpret_cast<const short8*>(A0 + kt * 4096);
            short8 af1 = *reinterpret_cast<const short8*>(A1 + kt * 4096);
            short8 bf0 = *reinterpret_cast<const short8*>(B0 + kt * 32);
            short8 bf1 = *reinterpret_cast<const short8*>(B1 + kt * 32);
            c00 = __builtin_amdgcn_mfma_f32_16x16x32_bf16(af0, bf0, c00, 0, 0, 0);
            c01 = __builtin_amdgcn_mfma_f32_16x16x32_bf16(af0, bf1, c01, 0, 0, 0);
            c10 = __builtin_amdgcn_mfma_f32_16x16x32_bf16(af1, bf0, c10, 0, 0, 0);
            c11 = __builtin_amdgcn_mfma_f32_16x16x32_bf16(af1, bf1, c11, 0, 0, 0);
        }

        int s0 = q0 - bb * DHW;
        float* outb = out + (size_t)bb * OUTCH * DHW + s0;
        int ocRow = (wid * 2) * 16 + q * 4;
        #pragma unroll
        for (int rg = 0; rg < 4; ++rg) {
            outb[(ocRow + rg) * DHW + l16]            = c00[rg];
            outb[(ocRow + rg) * DHW + 16 + l16]       = c01[rg];
            outb[(ocRow + 16 + rg) * DHW + l16]       = c10[rg];
            outb[(ocRow + 16 + rg) * DHW + 16 + l16]  = c11[rg];
        }

        // BN partial stats for this block's 32 points
        int slot = blockIdx.x & 63;
        #pragma unroll
        for (int rg = 0; rg < 4; ++rg) {
            float sA = c00[rg] + c01[rg];
            float qA = c00[rg] * c00[rg] + c01[rg] * c01[rg];
            float sB = c10[rg] + c11[rg];
            float qB = c10[rg] * c10[rg] + c11[rg] * c11[rg];
            #pragma unroll
            for (int m = 1; m < 16; m <<= 1) {
                sA += __shfl_xor(sA, m);
                qA += __shfl_xor(qA, m);
                sB += __shfl_xor(sB, m);
                qB += __shfl_xor(qB, m);
            }
            if (l16 == 0) {
                int chA = ocRow + rg;
                int chB = chA + 16;
                atomicAdd(&psq[chA * 64 + slot], sA);
                atomicAdd(&psq[8192 + chA * 64 + slot], qA);
                atomicAdd(&psq[chB * 64 + slot], sB);
                atomicAdd(&psq[8192 + chB * 64 + slot], qB);
            }
        }
    }
}

// ---- fold the 64 stat slots: partF[c] = sum, partF[128+c] = sumsq ----
__global__ __launch_bounds__(256) void k_reduce(const float* __restrict__ psq,
                                                float* __restrict__ partF) {
    int t = threadIdx.x;                 // 0..255; t<128 -> S of ch t; t>=128 -> Q of ch t-128
    const float* src = psq + (size_t)t * 64;   // Q region starts exactly at 128*64=8192 ✓
    float s = 0.f;
    #pragma unroll
    for (int i = 0; i < 64; ++i) s += src[i];
    partF[t] = s;
}

// ---- BN + SiLU in place ----
__global__ __launch_bounds__(256) void k_bn_silu(float* __restrict__ out,
                                                 const float* __restrict__ partF,
                                                 const float* __restrict__ gamma,
                                                 const float* __restrict__ beta) {
    int t = blockIdx.x * 256 + threadIdx.x;
    int base = t * 4;
    int c = (base / DHW) & 127;
    float sum = partF[c];
    float ss  = partF[128 + c];
    const float inv_n = 1.f / (float)(BATCH * DHW);
    float mean = sum * inv_n;
    float var  = ss * inv_n - mean * mean;
    float sc   = gamma[c] * rsqrtf(var + 1e-5f);
    float bi   = beta[c] - mean * sc;
    float4 v = *reinterpret_cast<float4*>(&out[base]);
    float y0 = fmaf(v.x, sc, bi);
    float y1 = fmaf(v.y, sc, bi);
    float y2 = fmaf(v.z, sc, bi);
    float y3 = fmaf(v.w, sc, bi);
    v.x = y0 / (1.f + expf(-y0));
    v.y = y1 / (1.f + expf(-y1));
    v.z = y2 / (1.f + expf(-y2));
    v.w = y3 / (1.f + expf(-y3));
    *reinterpret_cast<float4*>(&out[base]) = v;
}

extern "C" void kernel_launch(void* const* d_in, const int* in_sizes, int n_in,
                              void* d_out, int out_size, void* d_ws, size_t ws_size,
                              hipStream_t stream) {
    const float* x     = (const float*)d_in[0];
    const float* wp    = (const float*)d_in[1];
    const float* bp    = (const float*)d_in[2];
    const float* wc    = (const float*)d_in[3];
    const float* gamma = (const float*)d_in[4];
    const float* beta  = (const float*)d_in[5];
    float* out = (float*)d_out;
    float* ws  = (float*)d_ws;

    ushort*   w2b  = reinterpret_cast<ushort*>(ws + WS_W2B);
    float*    w3c  = ws + WS_W3;
    unsigned* xTu  = reinterpret_cast<unsigned*>(ws + WS_XT);
    float*    off  = ws + WS_OFF;
    float*    psq  = ws + WS_PSQ;
    float*    pF   = ws + WS_PF;

    k_prep_w2b<<<65536 / 256, 256, 0, stream>>>(wc, w2b);
    k_prep_w3<<<55296 / 256, 256, 0, stream>>>(wp, w3c, psq);
    k_conv<<<SPTS / 128, 256, 0, stream>>>(x, w3c, bp, off);
    k_transpose_x<<<SPTS / 64, 256, 0, stream>>>(x, xTu);
    k_fused<<<SPTS / 32, 256, 0, stream>>>(xTu, off, w2b, out, psq);
    k_reduce<<<1, 256, 0, stream>>>(psq, pF);
    k_bn_silu<<<(NELEM / 4) / 256, 256, 0, stream>>>(out, pF, gamma, beta);
}

// Round 17
// 241.248 us; speedup vs baseline: 1.0390x; 1.0390x over previous
//
#include <hip/hip_runtime.h>
#include <math.h>

#define BATCH 2
#define INC   64
#define OUTCH 128
#define NP    8
#define DD    12
#define HH    48
#define WW    48
#define HW    (HH*WW)         // 2304
#define DHW   (DD*HW)         // 27648
#define SPTS  (BATCH*DHW)     // 55296
#define KDIM  (INC*NP)        // 512
#define NELEM (BATCH*OUTCH*DHW) // 7077888
#define VSTRIDE 516           // bf16 elems per p-row in LDS for GEMM2 B (usage 512, pad 4)

// workspace layout (floats) — total 3,186,688 floats = 12.75 MB
#define WS_W2B  0                          // ushort[65536]: GEMM2 A bf16 fragments
#define WS_W3   32768                      // float[55296]: conv weights [ic][27][32] (24 used)
#define WS_PART 88064                      // 2048 floats: psum/psq partials
#define WS_XT   90112                      // uint[1769472]: x as [b][s][ic/2] bf16x2
#define WS_OFF  1859584                    // float[SPTS*24]: offset-conv output [s][24]

typedef __attribute__((ext_vector_type(8))) short short8;
typedef __attribute__((ext_vector_type(4))) float floatx4;

__device__ __forceinline__ ushort f2bf(float f) {
    unsigned u = __float_as_uint(f);
    unsigned r = (u + 0x7fffu + ((u >> 16) & 1u)) >> 16;
    return (ushort)r;
}

__device__ __forceinline__ unsigned interp2(unsigned a, unsigned b, unsigned c, unsigned d,
                                            float g0, float g1, float g2, float g3) {
    float vl = g0 * __uint_as_float(a << 16) + g1 * __uint_as_float(b << 16)
             + g2 * __uint_as_float(c << 16) + g3 * __uint_as_float(d << 16);
    float vh = g0 * __uint_as_float(a & 0xffff0000u) + g1 * __uint_as_float(b & 0xffff0000u)
             + g2 * __uint_as_float(c & 0xffff0000u) + g3 * __uint_as_float(d & 0xffff0000u);
    return (unsigned)f2bf(vl) | ((unsigned)f2bf(vh) << 16);
}

// ---- prep (merged): blocks [0,256) build w2b; blocks [256,472) build w3c.
// Both bodies byte-identical to the proven standalone kernels; disjoint outputs.
__global__ __launch_bounds__(256) void k_prep(const float* __restrict__ wc,
                                              const float* __restrict__ wp,
                                              ushort* __restrict__ w2b,
                                              float* __restrict__ w3c) {
    int blk = blockIdx.x;
    if (blk < 256) {
        int t = blk * 256 + threadIdx.x;      // 65536
        int j  = t & 7;
        int oc = (t >> 3) & 127;
        int kq = t >> 10;
        int e  = kq * 8 + j;
        int ic = e & 63;
        int n  = e >> 6;
        w2b[t] = f2bf(wc[(oc * INC + ic) * NP + n]);
    } else {
        int t = (blk - 256) * 256 + threadIdx.x;   // 55296
        int ch = t & 31;
        int iu = t >> 5;                      // ic*27+tt, 0..1727
        w3c[t] = (ch < 24) ? wp[ch * 1728 + iu] : 0.f;
    }
}

// ---- prep 0c v2: LDS tile transpose — coalesced reads (was stride-221KB scatter).
// Block = one batch-local 64-s x 64-ic tile. Output bit-identical to the original
// scatter kernel: same f2bf on the same floats, same layout.
__global__ __launch_bounds__(256) void k_transpose_x(const float* __restrict__ x,
                                                     unsigned* __restrict__ xTu) {
    __shared__ float sX[64 * 65];             // 16,640 B; pad 65 breaks bank aliasing
    int t  = threadIdx.x;
    int q0 = blockIdx.x * 64;                 // DHW%64==0 -> tile in one batch
    int bb = q0 / DHW;
    int s0 = q0 - bb * DHW;
    const float* xb = x + (size_t)bb * INC * DHW + s0;

    int si  = t & 63;
    int icL = t >> 6;                         // 0..3
    #pragma unroll
    for (int k = 0; k < 16; ++k) {
        int ic = k * 4 + icL;
        sX[ic * 65 + si] = xb[(size_t)ic * DHW + si];
    }
    __syncthreads();

    int icp = t & 31;
    int sjb = t >> 5;                         // 0..7
    #pragma unroll
    for (int pass = 0; pass < 8; ++pass) {
        int sj = pass * 8 + sjb;
        float v0 = sX[(2 * icp)     * 65 + sj];
        float v1 = sX[(2 * icp + 1) * 65 + sj];
        xTu[(size_t)(q0 + sj) * 32 + icp] = (unsigned)f2bf(v0) | ((unsigned)f2bf(v1) << 16);
    }
}

// ---- standalone fp32 offset conv: R7 champion, byte-identical (123us floor, proven).
// CRITICAL NUMERIC INVARIANT (R2 failure): each channel's fmaf chain must be bitwise
// identical to the original — seed bp[ch], then fmaf over (kz, ic=0..63, u=0..8)
// lexicographic, all within ONE thread. Only points and channels split across threads.
// Scoreboard R7..R14: all restructurings land 123-151us; 123 is the floor — frozen.
__global__ __launch_bounds__(256, 4) void k_conv(const float* __restrict__ x,
                                                 const float* __restrict__ w3c,
                                                 const float* __restrict__ bp,
                                                 float* __restrict__ off) {
    int t    = threadIdx.x;
    int lane = t & 63;
    int hgq  = __builtin_amdgcn_readfirstlane(t >> 6);   // 0..3: channel sextet, wave-uniform
    int q0 = blockIdx.x * 128;        // 128 pts/block; HW%128==0 -> one (batch, z-plane)
    int bb = q0 / DHW;
    int s0 = q0 - bb * DHW;
    int dp = s0 / HW;                 // block-uniform z
    int rp = s0 - dp * HW + 2 * lane;
    int hp = rp / WW;
    int c0 = rp - hp * WW;            // even, 0..46; pair never crosses a row (WW%2==0)
    const float* xb = x + (size_t)bb * INC * DHW;
    const float* wbase = w3c + hgq * 6;

    int rAo = (hp > 0      ? hp - 1 : 0     ) * WW;   // kx=0 row
    int rMo = hp * WW;                                // kx=1 row
    int rBo = (hp < HH - 1 ? hp + 1 : HH - 1) * WW;   // kx=2 row
    int oL = (c0 > 0)  ? c0 - 2 : 0;    // float2 holding col c0-1 (L.y)
    int oM = c0;                        // cols c0, c0+1
    int oR = (c0 < 46) ? c0 + 2 : 46;   // float2 holding col c0+2 (R.x)

    float rm0 = (hp > 0)      ? 1.f : 0.f;
    float rm2 = (hp < HH - 1) ? 1.f : 0.f;
    float clm = (c0 > 0)      ? 1.f : 0.f;   // pt0 ky=0 col mask
    float crm = (c0 < 46)     ? 1.f : 0.f;   // pt1 ky=2 col mask
    float m0[9], m1[9];
    #pragma unroll
    for (int kx = 0; kx < 3; ++kx) {
        float rmv = kx == 0 ? rm0 : (kx == 1 ? 1.f : rm2);
        #pragma unroll
        for (int ky = 0; ky < 3; ++ky) {
            int u = kx * 3 + ky;
            m0[u] = rmv * (ky == 0 ? clm : 1.f);
            m1[u] = rmv * (ky == 2 ? crm : 1.f);
        }
    }

    float acc[2][6];
    #pragma unroll
    for (int c = 0; c < 6; ++c) { acc[0][c] = bp[hgq * 6 + c]; acc[1][c] = bp[hgq * 6 + c]; }

    #pragma unroll 1
    for (int kz = 0; kz < 3; ++kz) {
        int z = dp + kz - 1;
        if ((unsigned)z >= DD) continue;     // block-uniform; skips only exact +-0 adds
        const float* xz = xb + z * HW;
        #pragma unroll 2
        for (int ic = 0; ic < 64; ++ic) {
            const float* xp = xz + (size_t)ic * DHW;
            float2 LA = *reinterpret_cast<const float2*>(xp + rAo + oL);
            float2 MA = *reinterpret_cast<const float2*>(xp + rAo + oM);
            float2 RA = *reinterpret_cast<const float2*>(xp + rAo + oR);
            float2 LM = *reinterpret_cast<const float2*>(xp + rMo + oL);
            float2 MM = *reinterpret_cast<const float2*>(xp + rMo + oM);
            float2 RM = *reinterpret_cast<const float2*>(xp + rMo + oR);
            float2 LB = *reinterpret_cast<const float2*>(xp + rBo + oL);
            float2 MB = *reinterpret_cast<const float2*>(xp + rBo + oM);
            float2 RB = *reinterpret_cast<const float2*>(xp + rBo + oR);
            const float* wk = wbase + (ic * 27 + kz * 9) * 32;
            #pragma unroll
            for (int kx = 0; kx < 3; ++kx) {
                float tv[4];
                if (kx == 0)      { tv[0] = LA.y; tv[1] = MA.x; tv[2] = MA.y; tv[3] = RA.x; }
                else if (kx == 1) { tv[0] = LM.y; tv[1] = MM.x; tv[2] = MM.y; tv[3] = RM.x; }
                else              { tv[0] = LB.y; tv[1] = MB.x; tv[2] = MB.y; tv[3] = RB.x; }
                #pragma unroll
                for (int ky = 0; ky < 3; ++ky) {
                    int u = kx * 3 + ky;
                    const float* w6 = wk + u * 32;
                    float xv0 = tv[ky]     * m0[u];
                    float xv1 = tv[ky + 1] * m1[u];
                    #pragma unroll
                    for (int c = 0; c < 6; ++c) {
                        acc[0][c] = fmaf(xv0, w6[c], acc[0][c]);
                        acc[1][c] = fmaf(xv1, w6[c], acc[1][c]);
                    }
                }
            }
        }
    }

    float2* o0 = reinterpret_cast<float2*>(off + (size_t)(q0 + 2 * lane) * 24 + hgq * 6);
    o0[0] = make_float2(acc[0][0], acc[0][1]);
    o0[1] = make_float2(acc[0][2], acc[0][3]);
    o0[2] = make_float2(acc[0][4], acc[0][5]);
    float2* o1 = reinterpret_cast<float2*>(off + (size_t)(q0 + 2 * lane + 1) * 24 + hgq * 6);
    o1[0] = make_float2(acc[1][0], acc[1][1]);
    o1[1] = make_float2(acc[1][2], acc[1][3]);
    o1[2] = make_float2(acc[1][4], acc[1][5]);
}

// ---- fused v2 (R15-proven): geometry + barrier-free direct gather-interp + MFMA GEMM2.
// No stats fusion (R16 lesson: the atomicAdd chains + extra launch cost >= the 12us
// saved from skipping the out re-read — reverted).
__global__ __launch_bounds__(256, 4) void k_fused(const unsigned* __restrict__ xTu,
                                                  const float* __restrict__ off,
                                                  const ushort* __restrict__ w2b,
                                                  float* __restrict__ out) {
    __shared__ __align__(16) ushort sVb[32 * VSTRIDE];   // 33,024 B: V[p][e] bf16
    __shared__ __align__(16) ushort4 sMiP[256];          // 2 KB: 4 corner indices per task
    __shared__ __align__(16) float4  sMgP[256];          // 4 KB: 4 corner weights per task

    int t  = threadIdx.x;
    int q0 = blockIdx.x * 32;        // DHW%32==0 -> block never straddles batch
    int bb = q0 / DHW;

    // ---- geometry (fp32), task t = (i = t>>3, n = t&7): publish corner meta to LDS ----
    {
        int i = t >> 3, n = t & 7;
        int s = q0 + i - bb * DHW;
        int d = s / HW; int r = s - d * HW; int h = r / WW; int w = r - h * WW;

        const float* op = off + (size_t)(q0 + i) * 24;
        float a0 = op[n];
        float a1 = op[8 + n];
        float a2 = op[16 + n];

        float pnz = (n < 6) ? (float)(n / 3) : 2.f;
        float pnx = (n < 6) ? 0.f : 1.f;
        float pny = (n < 6) ? (float)(n % 3) : (float)(n - 6);
        float pz = a0 + (float)d + pnz;
        float px = a1 + (float)h + pnx;
        float py = a2 + (float)w + pny;
        float fz = floorf(pz), fx = floorf(px), fy = floorf(py);
        float z0 = fminf(fmaxf(fz, 0.f), DD - 1.f), z1 = fminf(fmaxf(fz + 1.f, 0.f), DD - 1.f);
        float x0 = fminf(fmaxf(fx, 0.f), HH - 1.f), x1 = fminf(fmaxf(fx + 1.f, 0.f), HH - 1.f);
        float y0 = fminf(fmaxf(fy, 0.f), WW - 1.f), y1 = fminf(fmaxf(fy + 1.f, 0.f), WW - 1.f);
        float pzc = fminf(fmaxf(pz, 0.f), DD - 1.f);
        float pxc = fminf(fmaxf(px, 0.f), HH - 1.f);
        float pyc = fminf(fmaxf(py, 0.f), WW - 1.f);
        float wz0 = 1.f + z0 - pzc, wz1 = 1.f - z1 + pzc;
        float wx0 = 1.f + x0 - pxc, wx1 = 1.f - x1 + pxc;
        float wy0 = 1.f + y0 - pyc, wy1 = 1.f - y1 + pyc;
        float c0 = wz0 * wy0, c1 = wz1 * wy1;
        int iz0 = (int)z0, iz1 = (int)z1, ix0 = (int)x0, ix1 = (int)x1, iy0 = (int)y0, iy1 = (int)y1;
        ushort i0 = (ushort)((iz0 * HH + ix0) * WW + iy0);
        ushort i1 = (ushort)((iz0 * HH + ix1) * WW + iy0);
        ushort i2 = (ushort)((iz1 * HH + ix0) * WW + iy1);
        ushort i3 = (ushort)((iz1 * HH + ix1) * WW + iy1);
        sMiP[t] = make_ushort4(i0, i1, i2, i3);
        sMgP[t] = make_float4(c0 * wx0, c0 * wx1, c1 * wx0, c1 * wx1);
    }
    __syncthreads();   // meta ready

    // ---- phase 2: barrier-free direct gather + interp (8 chunks x 32 tasks) ----
    {
        const unsigned* xTb = xTu + (size_t)bb * DHW * 32;
        unsigned* sVbU = reinterpret_cast<unsigned*>(sVb);
        int tk = t >> 3, ch8 = t & 7;    // task-local (0..31), 8-ch octet (0..7)

        #pragma unroll 4
        for (int cc = 0; cc < 8; ++cc) {
            int gt = cc * 32 + tk;
            ushort4 mi = sMiP[gt];       // broadcast ds_read (8 lanes same addr)
            float4  mg = sMgP[gt];
            uint4 A = *reinterpret_cast<const uint4*>(xTb + (size_t)mi.x * 32 + ch8 * 4);
            uint4 B = *reinterpret_cast<const uint4*>(xTb + (size_t)mi.y * 32 + ch8 * 4);
            uint4 C = *reinterpret_cast<const uint4*>(xTb + (size_t)mi.z * 32 + ch8 * 4);
            uint4 D = *reinterpret_cast<const uint4*>(xTb + (size_t)mi.w * 32 + ch8 * 4);
            unsigned o0 = interp2(A.x, B.x, C.x, D.x, mg.x, mg.y, mg.z, mg.w);
            unsigned o1 = interp2(A.y, B.y, C.y, D.y, mg.x, mg.y, mg.z, mg.w);
            unsigned o2 = interp2(A.z, B.z, C.z, D.z, mg.x, mg.y, mg.z, mg.w);
            unsigned o3 = interp2(A.w, B.w, C.w, D.w, mg.x, mg.y, mg.z, mg.w);
            int ii = gt >> 3, nn = gt & 7;
            int wb = ii * (VSTRIDE / 2) + nn * 32 + ch8 * 4;   // even -> 8B aligned
            *reinterpret_cast<uint2*>(&sVbU[wb])     = make_uint2(o0, o1);
            *reinterpret_cast<uint2*>(&sVbU[wb + 2]) = make_uint2(o2, o3);
        }
    }
    __syncthreads();   // sVb complete

    // ---- phase 3: out[128oc x 32p] via mfma_f32_16x16x32_bf16 ----
    {
        int lane = t & 63;
        int wid  = t >> 6;
        int l16  = lane & 15;
        int q    = lane >> 4;
        int ocA0 = (wid * 2) * 16 + l16;
        const ushort* A0 = w2b + ((q * 128) + ocA0) * 8;     // +kt*4096
        const ushort* A1 = A0 + 16 * 8;
        const ushort* B0 = sVb + l16 * VSTRIDE + q * 8;      // +kt*32
        const ushort* B1 = B0 + 16 * VSTRIDE;

        floatx4 c00 = {0.f, 0.f, 0.f, 0.f};
        floatx4 c01 = {0.f, 0.f, 0.f, 0.f};
        floatx4 c10 = {0.f, 0.f, 0.f, 0.f};
        floatx4 c11 = {0.f, 0.f, 0.f, 0.f};

        #pragma unroll 4
        for (int kt = 0; kt < 16; ++kt) {
            short8 af0 = *reinterpret_cast<const short8*>(A0 + kt * 4096);
            short8 af1 = *reinterpret_cast<const short8*>(A1 + kt * 4096);
            short8 bf0 = *reinterpret_cast<const short8*>(B0 + kt * 32);
            short8 bf1 = *reinterpret_cast<const short8*>(B1 + kt * 32);
            c00 = __builtin_amdgcn_mfma_f32_16x16x32_bf16(af0, bf0, c00, 0, 0, 0);
            c01 = __builtin_amdgcn_mfma_f32_16x16x32_bf16(af0, bf1, c01, 0, 0, 0);
            c10 = __builtin_amdgcn_mfma_f32_16x16x32_bf16(af1, bf0, c10, 0, 0, 0);
            c11 = __builtin_amdgcn_mfma_f32_16x16x32_bf16(af1, bf1, c11, 0, 0, 0);
        }

        int s0 = q0 - bb * DHW;
        float* outb = out + (size_t)bb * OUTCH * DHW + s0;
        int ocRow = (wid * 2) * 16 + q * 4;
        #pragma unroll
        for (int rg = 0; rg < 4; ++rg) {
            outb[(ocRow + rg) * DHW + l16]            = c00[rg];
            outb[(ocRow + rg) * DHW + 16 + l16]       = c01[rg];
            outb[(ocRow + 16 + rg) * DHW + l16]       = c10[rg];
            outb[(ocRow + 16 + rg) * DHW + 16 + l16]  = c11[rg];
        }
    }
}

// ---- BN stats: deterministic partial sums ----
__global__ __launch_bounds__(256) void k_stats_partial(const float* __restrict__ out,
                                                       float* __restrict__ part) {
    int c = blockIdx.x >> 3;
    int j = blockIdx.x & 7;
    int b = j & 1, quarter = j >> 1;
    const float4* p = reinterpret_cast<const float4*>(
        out + (size_t)(b * OUTCH + c) * DHW + quarter * (DHW / 4));
    float sum = 0.f, ss = 0.f;
    for (int s = threadIdx.x; s < DHW / 16; s += 256) {
        float4 v = p[s];
        sum += v.x + v.y + v.z + v.w;
        ss = fmaf(v.x, v.x, ss); ss = fmaf(v.y, v.y, ss);
        ss = fmaf(v.z, v.z, ss); ss = fmaf(v.w, v.w, ss);
    }
    __shared__ float r1[256], r2[256];
    r1[threadIdx.x] = sum; r2[threadIdx.x] = ss;
    __syncthreads();
    for (int ofs = 128; ofs > 0; ofs >>= 1) {
        if (threadIdx.x < ofs) {
            r1[threadIdx.x] += r1[threadIdx.x + ofs];
            r2[threadIdx.x] += r2[threadIdx.x + ofs];
        }
        __syncthreads();
    }
    if (threadIdx.x == 0) {
        part[c * 8 + j]             = r1[0];
        part[OUTCH * 8 + c * 8 + j] = r2[0];
    }
}

// ---- BN + SiLU in place ----
__global__ __launch_bounds__(256) void k_bn_silu(float* __restrict__ out,
                                                 const float* __restrict__ part,
                                                 const float* __restrict__ gamma,
                                                 const float* __restrict__ beta) {
    int t = blockIdx.x * 256 + threadIdx.x;
    int base = t * 4;
    int c = (base / DHW) & 127;
    float sum = 0.f, ss = 0.f;
    #pragma unroll
    for (int j = 0; j < 8; ++j) {
        sum += part[c * 8 + j];
        ss  += part[OUTCH * 8 + c * 8 + j];
    }
    const float inv_n = 1.f / (float)(BATCH * DHW);
    float mean = sum * inv_n;
    float var  = ss * inv_n - mean * mean;
    float sc   = gamma[c] * rsqrtf(var + 1e-5f);
    float bi   = beta[c] - mean * sc;
    float4 v = *reinterpret_cast<float4*>(&out[base]);
    float y0 = fmaf(v.x, sc, bi);
    float y1 = fmaf(v.y, sc, bi);
    float y2 = fmaf(v.z, sc, bi);
    float y3 = fmaf(v.w, sc, bi);
    v.x = y0 / (1.f + expf(-y0));
    v.y = y1 / (1.f + expf(-y1));
    v.z = y2 / (1.f + expf(-y2));
    v.w = y3 / (1.f + expf(-y3));
    *reinterpret_cast<float4*>(&out[base]) = v;
}

extern "C" void kernel_launch(void* const* d_in, const int* in_sizes, int n_in,
                              void* d_out, int out_size, void* d_ws, size_t ws_size,
                              hipStream_t stream) {
    const float* x     = (const float*)d_in[0];
    const float* wp    = (const float*)d_in[1];
    const float* bp    = (const float*)d_in[2];
    const float* wc    = (const float*)d_in[3];
    const float* gamma = (const float*)d_in[4];
    const float* beta  = (const float*)d_in[5];
    float* out = (float*)d_out;
    float* ws  = (float*)d_ws;

    ushort*   w2b  = reinterpret_cast<ushort*>(ws + WS_W2B);
    float*    w3c  = ws + WS_W3;
    float*    part = ws + WS_PART;
    unsigned* xTu  = reinterpret_cast<unsigned*>(ws + WS_XT);
    float*    off  = ws + WS_OFF;

    k_prep<<<472, 256, 0, stream>>>(wc, wp, w2b, w3c);
    k_conv<<<SPTS / 128, 256, 0, stream>>>(x, w3c, bp, off);
    k_transpose_x<<<SPTS / 64, 256, 0, stream>>>(x, xTu);
    k_fused<<<SPTS / 32, 256, 0, stream>>>(xTu, off, w2b, out);
    k_stats_partial<<<OUTCH * 8, 256, 0, stream>>>(out, part);
    k_bn_silu<<<(NELEM / 4) / 256, 256, 0, stream>>>(out, part, gamma, beta);
}